// Round 1
// baseline (1785.294 us; speedup 1.0000x reference)
//
#include <hip/hip_runtime.h>

#define LROW   2904
#define PERIOD 24
#define CYC    121          // LROW / PERIOD
#define HW     6            // window 13 half-width
#define NT     256

__device__ __forceinline__ int clampi(int i) {
    return i < 0 ? 0 : (i >= LROW ? LROW - 1 : i);
}

// monotone (order-preserving) uint mapping of float
__device__ __forceinline__ unsigned sortable(float x) {
    unsigned u = __float_as_uint(x);
    return (u & 0x80000000u) ? ~u : (u | 0x80000000u);
}

// dst[l] = mean_{j=l-6..l+6} src[clamp(j,0,L-1)]  (replicate-pad MA, width 13)
// Thread t owns contiguous chunk [13t, 13t+13); sliding sum (2 LDS reads/output).
// Lane stride 13 is coprime to 32 banks -> conflict-free.
__device__ __forceinline__ void ma13(const float* src, float* dst, int t) {
    int l0 = t * 13;
    if (l0 >= LROW) return;
    int l1 = min(l0 + 13, LROW);
    float sum = 0.f;
    #pragma unroll
    for (int j = -HW; j <= HW; ++j) sum += src[clampi(l0 + j)];
    dst[l0] = sum * (1.f / 13.f);
    for (int l = l0 + 1; l < l1; ++l) {
        sum += src[clampi(l + HW)] - src[clampi(l - HW - 1)];
        dst[l] = sum * (1.f / 13.f);
    }
}

__global__ __launch_bounds__(NT) void stl_kernel(const float* __restrict__ x,
                                                 float* __restrict__ out,
                                                 int B, int F) {
    __shared__ float ls[LROW];   // s (input row)
    __shared__ float lt[LROW];   // trend
    __shared__ float ld[LROW];   // scratch: d = s - trend, then s - seasonal
    __shared__ float lmed[PERIOD];

    const int row = blockIdx.x;          // 0 .. B*F-1
    const int b = row / F;
    const int f = row - b * F;
    const int t = threadIdx.x;
    const size_t rowbase = (size_t)b * LROW * F + (size_t)f;

    // ---- load s (strided by F; rely on L2/L3 line reuse across f-adjacent blocks)
    for (int l = t; l < LROW; l += NT) ls[l] = x[rowbase + (size_t)l * F];
    __syncthreads();

    // ---- initial trend = MA13(s)
    ma13(ls, lt, t);
    __syncthreads();

    for (int iter = 0; iter < 2; ++iter) {
        // d = s - trend
        for (int l = t; l < LROW; l += NT) ld[l] = ls[l] - lt[l];
        __syncthreads();

        // ---- median over cycles for each of 24 phases: 8 threads/phase
        if (t < PERIOD * 8) {
            const int p   = t >> 3;
            const int sub = t & 7;
            const int c0  = sub * 16;          // sub 0..6 own 16, sub 7 owns 9
            unsigned key[16];
            #pragma unroll
            for (int i = 0; i < 16; ++i) {
                int c = c0 + i;
                key[i] = (c < CYC)
                    ? ((sortable(ld[c * PERIOD + p]) & 0xFFFFFF80u) | (unsigned)c)
                    : 0xFFFFFFFFu;             // pad: never rank 60
            }
            int cnt[16];
            #pragma unroll
            for (int i = 0; i < 16; ++i) cnt[i] = 0;
            #pragma unroll 4
            for (int cc = 0; cc < CYC; ++cc) {
                // broadcast read within each 8-thread phase group
                unsigned wk = (sortable(ld[cc * PERIOD + p]) & 0xFFFFFF80u) | (unsigned)cc;
                #pragma unroll
                for (int i = 0; i < 16; ++i) cnt[i] += (wk < key[i]) ? 1 : 0;
            }
            #pragma unroll
            for (int i = 0; i < 16; ++i) {
                if (cnt[i] == 60 && (c0 + i) < CYC)   // unique: keys are distinct
                    lmed[p] = ld[(c0 + i) * PERIOD + p];
            }
        }
        __syncthreads();

        // detrend input for next smooth: ld = s - seasonal
        for (int l = t; l < LROW; l += NT) ld[l] = ls[l] - lmed[l % PERIOD];
        __syncthreads();

        // trend = MA13(s - seasonal)
        ma13(ld, lt, t);
        __syncthreads();
    }

    // ---- outputs: trend, seasonal, residual in [B, L, F] layout, concatenated
    const size_t S = (size_t)B * LROW * F;
    for (int l = t; l < LROW; l += NT) {
        float tr = lt[l];
        float se = lmed[l % PERIOD];
        float re = ls[l] - tr - se;
        size_t o = rowbase + (size_t)l * F;
        out[o]         = tr;
        out[S + o]     = se;
        out[2 * S + o] = re;
    }
}

extern "C" void kernel_launch(void* const* d_in, const int* in_sizes, int n_in,
                              void* d_out, int out_size, void* d_ws, size_t ws_size,
                              hipStream_t stream) {
    const float* x = (const float*)d_in[0];
    float* out = (float*)d_out;
    const int B = 64, F = 207;   // in_sizes[0] == B * LROW * F == 38472192
    (void)in_sizes; (void)n_in; (void)out_size; (void)d_ws; (void)ws_size;
    hipLaunchKernelGGL(stl_kernel, dim3(B * F), dim3(NT), 0, stream, x, out, B, F);
}

// Round 2
// 1083.617 us; speedup vs baseline: 1.6475x; 1.6475x over previous
//
#include <hip/hip_runtime.h>

#define LROW   2904
#define PERIOD 24
#define CYC    121          // LROW / PERIOD (odd -> median = rank 60)
#define HW     6            // window 13 half-width
#define NT     256
#define NROWS  13248        // B * F = 64 * 207
#define CHUNK  (NROWS / 8)  // 1656 = 8 batches * 207 features per XCD

__device__ __forceinline__ int clampi(int i) {
    return i < 0 ? 0 : (i >= LROW ? LROW - 1 : i);
}

// monotone (order-preserving) uint mapping of float, and inverse
__device__ __forceinline__ unsigned sortable(float x) {
    unsigned u = __float_as_uint(x);
    return (u & 0x80000000u) ? ~u : (u | 0x80000000u);
}
__device__ __forceinline__ float unsortable(unsigned k) {
    unsigned u = (k & 0x80000000u) ? (k & 0x7FFFFFFFu) : ~k;
    return __uint_as_float(u);
}

// dst[l] = mean_{j=l-6..l+6} src[clamp(j)] ; thread t owns chunk [13t, 13t+13)
// lane stride 13 words is coprime to 32 banks -> conflict-free
__device__ __forceinline__ void ma13(const float* src, float* dst, int t) {
    int l0 = t * 13;
    if (l0 >= LROW) return;
    int l1 = min(l0 + 13, LROW);
    float sum = 0.f;
    #pragma unroll
    for (int j = -HW; j <= HW; ++j) sum += src[clampi(l0 + j)];
    dst[l0] = sum * (1.f / 13.f);
    for (int l = l0 + 1; l < l1; ++l) {
        sum += src[clampi(l + HW)] - src[clampi(l - HW - 1)];
        dst[l] = sum * (1.f / 13.f);
    }
}

__global__ __launch_bounds__(NT) void stl_kernel(const float* __restrict__ x,
                                                 float* __restrict__ out) {
    __shared__ float    ls[LROW];    // input row s
    __shared__ float    lt[LROW];    // trend
    __shared__ unsigned lk[LROW];    // sort keys; reused as float scratch (s - seasonal)
    __shared__ float    lmed[PERIOD];
    float* lkf = (float*)lk;

    // chunked XCD swizzle: dispatch d -> XCD d%8; give each XCD a contiguous
    // logical range so adjacent-f blocks share an L2 (write-combine 64B lines,
    // no store-miss RMW). NROWS % 8 == 0 -> bijective.
    const int d   = blockIdx.x;
    const int row = (d & 7) * CHUNK + (d >> 3);
    const int b = row / 207;
    const int f = row - b * 207;
    const int t = threadIdx.x;
    const size_t rowbase = (size_t)b * (LROW * 207) + (size_t)f;

    // ---- load s (strided by F=207; L2-combined thanks to swizzle)
    for (int l = t; l < LROW; l += NT) ls[l] = x[rowbase + (size_t)l * 207];
    __syncthreads();

    // ---- initial trend = MA13(s)
    ma13(ls, lt, t);
    __syncthreads();

    for (int iter = 0; iter < 2; ++iter) {
        // ---- keys: lk[l] = (sortable(s-trend) & ~0x7F) | cycle_index
        // incremental (c,p) tracking: l += 256 => p += 16 mod 24, c += 10 (+1 on wrap)
        {
            int l = t, c = t / PERIOD, p = t - c * PERIOD;
            while (l < LROW) {
                lk[l] = (sortable(ls[l] - lt[l]) & 0xFFFFFF80u) | (unsigned)c;
                l += NT;
                p += 16; c += 10;
                if (p >= PERIOD) { p -= PERIOD; c += 1; }
            }
        }
        __syncthreads();

        // ---- median per phase: 8 threads/phase, counting-rank (keys unique)
        if (t < PERIOD * 8) {
            const int p   = t >> 3;
            const int sub = t & 7;
            const int c0  = sub * 16;          // sub 0..6 own 16, sub 7 owns 9
            unsigned key[16];
            #pragma unroll
            for (int i = 0; i < 16; ++i) {
                int c = c0 + i;
                key[i] = (c < CYC) ? lk[c * PERIOD + p] : 0xFFFFFFFFu;
            }
            int cnt[16];
            #pragma unroll
            for (int i = 0; i < 16; ++i) cnt[i] = 0;
            #pragma unroll 4
            for (int cc = 0; cc < CYC; ++cc) {
                unsigned wk = lk[cc * PERIOD + p];
                #pragma unroll
                for (int i = 0; i < 16; ++i) cnt[i] += (wk < key[i]) ? 1 : 0;
            }
            #pragma unroll
            for (int i = 0; i < 16; ++i) {
                if (cnt[i] == (CYC - 1) / 2 && (c0 + i) < CYC)
                    lmed[p] = unsortable(key[i] & 0xFFFFFF80u);
            }
        }
        __syncthreads();

        // ---- detrend for next smooth: lkf[l] = s - seasonal (overwrites keys)
        {
            int l = t, c = t / PERIOD, p = t - c * PERIOD;
            while (l < LROW) {
                lkf[l] = ls[l] - lmed[p];
                l += NT;
                p += 16;
                if (p >= PERIOD) p -= PERIOD;
            }
        }
        __syncthreads();

        // ---- trend = MA13(s - seasonal)
        ma13(lkf, lt, t);
        __syncthreads();
    }

    // ---- outputs: trend, seasonal, residual (each [B, L, F], concatenated)
    const size_t S = (size_t)NROWS * LROW;
    {
        int l = t, c = t / PERIOD, p = t - c * PERIOD;
        while (l < LROW) {
            float tr = lt[l];
            float se = lmed[p];
            float re = ls[l] - tr - se;
            size_t o = rowbase + (size_t)l * 207;
            out[o]         = tr;
            out[S + o]     = se;
            out[2 * S + o] = re;
            l += NT;
            p += 16;
            if (p >= PERIOD) p -= PERIOD;
        }
    }
}

extern "C" void kernel_launch(void* const* d_in, const int* in_sizes, int n_in,
                              void* d_out, int out_size, void* d_ws, size_t ws_size,
                              hipStream_t stream) {
    const float* x = (const float*)d_in[0];
    float* out = (float*)d_out;
    (void)in_sizes; (void)n_in; (void)out_size; (void)d_ws; (void)ws_size;
    hipLaunchKernelGGL(stl_kernel, dim3(NROWS), dim3(NT), 0, stream, x, out);
}